// Round 25
// baseline (1553.359 us; speedup 1.0000x reference)
//
#include <hip/hip_runtime.h>
#include <cstdint>
#include <cstddef>

#define NE   1024    // N_EMBD
#define DF   4096    // D_FF
#define KACT 1024    // K_ACTIVE
#define NTOK 16384   // B*S

typedef _Float16       f16x8  __attribute__((ext_vector_type(8)));
typedef unsigned short u16x8  __attribute__((ext_vector_type(8)));
typedef float          f32x4  __attribute__((ext_vector_type(4)));

#define MFMA16(a,b,c) __builtin_amdgcn_mfma_f32_16x16x32_f16(a,b,c,0,0,0)

// async global->LDS, 16B per lane; LDS dest = uniform base + lane*16 (linear)
#define GLD16(gp, lp) __builtin_amdgcn_global_load_lds( \
    (const __attribute__((address_space(1))) unsigned int*)(gp), \
    (__attribute__((address_space(3))) unsigned int*)(lp), 16, 0, 0)

// LDS tiles are [rows][32] f16 (64 B rows, 4x 16B chunks).
// 16x16 frags + sigma=(r>>1)&3: measured 0 bank conflicts (r10-r24).
// global_load_lds fills linearly; the same involution pre-swizzles the
// per-lane GLOBAL source chunk (rule 21).
__device__ __forceinline__ int sigma(int row) {
    return (row >> 1) & 3;
}
__device__ __forceinline__ int swz(int row, int lk) {
    return row * 32 + ((((lk) >> 3) ^ sigma(row)) << 3);
}

// ---------------------------------------------------------------------------
// Fused prep (1 launch): Wg->gh, Wu->uh, Wd->wdh, x->xh (all fp32->fp16).
// r25: xl dropped — single-fp16 gu. Selection-key noise rises 3.1e-4 ->
// 4.2e-4 (x-quant term added); extrapolated absmax ~0.059-0.065 < 0.06875.
// ---------------------------------------------------------------------------
__global__ __launch_bounds__(256) void k_prep(
    const float* __restrict__ Wg, const float* __restrict__ Wu,
    const float* __restrict__ Wd, const float* __restrict__ x,
    _Float16* __restrict__ gh, _Float16* __restrict__ uh,
    _Float16* __restrict__ wdh, _Float16* __restrict__ xh,
    int nw8, int nx8)
{
    int i = blockIdx.x * 256 + threadIdx.x;
    const float* s; _Float16* dh; int j;
    if (i < nw8)            { s = Wg; dh = gh;  j = i; }
    else if (i < 2*nw8)     { s = Wu; dh = uh;  j = i - nw8; }
    else if (i < 3*nw8)     { s = Wd; dh = wdh; j = i - 2*nw8; }
    else if (i < 3*nw8+nx8) { s = x;  dh = xh;  j = i - 3*nw8; }
    else return;
    float4 a = ((const float4*)s)[2*j], b = ((const float4*)s)[2*j+1];
    float f[8] = {a.x,a.y,a.z,a.w,b.x,b.y,b.z,b.w};
    f16x8 hh;
    #pragma unroll
    for (int q = 0; q < 8; ++q) hh[q] = (_Float16)f[q];
    ((f16x8*)dh)[j] = hh;
}

// ---------------------------------------------------------------------------
// Up-projection, SINGLE-fp16 MFMA (r25: xl term dropped — half the MFMA
// work of r23). 16x16x32 frags, 128x128 tile, 512 threads, 8 waves (2x4),
// per-wave 64 tok x 32 ff for g and u: 16 MFMA16 + 8 ds_read + 3 GLD16/lane
// per K-step. LDS per buf: XH/GH/UH [128][32] = 24KB; x2 = 48KB ->
// 3 blocks/CU -> 6 waves/SIMD.
// ---------------------------------------------------------------------------
#define OXH 0
#define OGH (128*32)
#define OUH (2*128*32)
#define GUBUF (3*128*32)   // 12288 elements = 24KB

__global__ __launch_bounds__(512, 6) void k_gemm_gu_mfma(
    const _Float16* __restrict__ xh,
    const _Float16* __restrict__ gh, const _Float16* __restrict__ uh,
    _Float16* __restrict__ z, int nM)
{
    __shared__ _Float16 L[2 * GUBUF];
    const int t = threadIdx.x, lane = t & 63, wid = t >> 6;   // wid 0..7

    // 4x4 supertile swizzle for L2 locality
    int bid = blockIdx.x, mi, ni;
    if ((nM & 3) == 0) {
        int st = bid >> 4, lo = bid & 15, nstM = nM >> 2;
        mi = ((st % nstM) << 2) + (lo & 3);
        ni = ((st / nstM) << 2) + (lo >> 2);
    } else { mi = bid % nM; ni = bid / nM; }
    const int m0 = mi * 128, f0 = ni * 128;

    // staging: thread t fills row t>>2, chunk t&3 (linear in t); wave w
    // covers rows [w*16, w*16+16). Source chunk pre-swizzled.
    const int rr = t >> 2, slot = t & 3;
    const int ss = slot ^ sigma(rr);
    const size_t xoff = (size_t)(m0 + rr) * (NE*2) + ss*16;
    const size_t goff = (size_t)(f0 + rr) * (NE*2) + ss*16;
    const char* xhB = (const char*)xh;
    const char* ghB = (const char*)gh;
    const char* uhB = (const char*)uh;

    const int wr = wid >> 2, wc = wid & 3;   // 2 x 4 wave grid
    const int lrow = lane & 15, lk = (lane >> 4) * 8;   // 16x16 frag coords

    int aoff[4], boff[2];
    #pragma unroll
    for (int mf = 0; mf < 4; ++mf)
        aoff[mf] = swz(wr*64 + mf*16 + lrow, lk);
    #pragma unroll
    for (int nf = 0; nf < 2; ++nf)
        boff[nf] = swz(wc*32 + nf*16 + lrow, lk);

    f32x4 accg[4][2] = {}, accu[4][2] = {};

    #define GU_STAGE(b, kt) do {                                              \
        _Float16* Lb = L + (b) * GUBUF;                                       \
        const size_t ka = (size_t)(kt) * 64;                                  \
        GLD16(xhB + xoff + ka, Lb + OXH + (wid*16)*32);                       \
        GLD16(ghB + goff + ka, Lb + OGH + (wid*16)*32);                       \
        GLD16(uhB + goff + ka, Lb + OUH + (wid*16)*32);                       \
    } while (0)

    GU_STAGE(0, 0);
    __syncthreads();

    int buf = 0;
    for (int kt = 0; kt < 32; ++kt) {
        if (kt + 1 < 32) GU_STAGE(buf ^ 1, kt + 1);
        const _Float16* Lb = &L[buf * GUBUF];
        f16x8 bg[2], bu[2];
        #pragma unroll
        for (int nf = 0; nf < 2; ++nf) {
            bg[nf] = *(const f16x8*)&Lb[OGH + boff[nf]];
            bu[nf] = *(const f16x8*)&Lb[OUH + boff[nf]];
        }
        #pragma unroll
        for (int mf = 0; mf < 4; ++mf) {
            f16x8 ah = *(const f16x8*)&Lb[OXH + aoff[mf]];
            #pragma unroll
            for (int nf = 0; nf < 2; ++nf) {
                accg[mf][nf] = MFMA16(ah, bg[nf], accg[mf][nf]);
                accu[mf][nf] = MFMA16(ah, bu[nf], accu[mf][nf]);
            }
        }
        __syncthreads();
        buf ^= 1;
    }

    // epilogue: silu(g)*u with native exp; 16x16 C-layout store
    #pragma unroll
    for (int mf = 0; mf < 4; ++mf)
        #pragma unroll
        for (int nf = 0; nf < 2; ++nf)
            #pragma unroll
            for (int r = 0; r < 4; ++r) {
                int row = m0 + wr*64 + mf*16 + (lane>>4)*4 + r;
                int col = f0 + wc*32 + nf*16 + lrow;
                float g = accg[mf][nf][r], u = accu[mf][nf][r];
                float sg = g / (1.0f + __expf(-g));
                z[(size_t)row*DF + col] = (_Float16)(sg * u);
            }
    #undef GU_STAGE
}

// ---------------------------------------------------------------------------
// Exact per-token top-K mask on fp16 z: 2-pass radix select on the 15-bit
// magnitude key; stable ties by ascending index. Masks in place. (r10-verified)
// ---------------------------------------------------------------------------
__global__ __launch_bounds__(256) void k_topk_mask16(_Float16* __restrict__ z)
{
    __shared__ unsigned short zrow[DF];
    __shared__ unsigned hist[256];
    __shared__ int      cnts[256];
    __shared__ unsigned s_b1;
    __shared__ unsigned s_tkey;
    __shared__ int      s_remaining;

    const int t = threadIdx.x;
    unsigned short* zp = (unsigned short*)(z + (size_t)blockIdx.x * DF);

    for (int i = t; i < DF/8; i += 256) {
        ((ushort4*)zrow)[2*i]   = ((const ushort4*)zp)[2*i];
        ((ushort4*)zrow)[2*i+1] = ((const ushort4*)zp)[2*i+1];
    }
    if (t == 0) s_remaining = KACT;
    __syncthreads();

    hist[t] = 0u;
    __syncthreads();
    {
        const int base = t * 16;
        #pragma unroll
        for (int j = 0; j < 16; ++j) {
            unsigned key = zrow[base + j] & 0x7FFFu;
            atomicAdd(&hist[key >> 7], 1u);
        }
    }
    __syncthreads();
    if (t == 0) {
        int rem = s_remaining;
        int b = 255;
        for (; b > 0; --b) {
            int c = (int)hist[b];
            if (rem - c <= 0) break;
            rem -= c;
        }
        s_b1 = (unsigned)b;
        s_remaining = rem;
    }
    __syncthreads();

    const unsigned b1 = s_b1;
    hist[t] = 0u;
    __syncthreads();
    {
        const int base = t * 16;
        #pragma unroll
        for (int j = 0; j < 16; ++j) {
            unsigned key = zrow[base + j] & 0x7FFFu;
            if ((key >> 7) == b1) atomicAdd(&hist[key & 0x7Fu], 1u);
        }
    }
    __syncthreads();
    if (t == 0) {
        int rem = s_remaining;
        int b = 127;
        for (; b > 0; --b) {
            int c = (int)hist[b];
            if (rem - c <= 0) break;
            rem -= c;
        }
        s_tkey = (b1 << 7) | (unsigned)b;
        s_remaining = rem;
    }
    __syncthreads();

    const unsigned tkey = s_tkey;
    const int      E    = s_remaining;

    const int base = t * 16;
    int cnt = 0;
    #pragma unroll
    for (int j = 0; j < 16; ++j)
        if ((zrow[base + j] & 0x7FFFu) == tkey) cnt++;
    cnts[t] = cnt;
    __syncthreads();
    if (t == 0) {
        int run = 0;
        for (int i = 0; i < 256; ++i) { int c = cnts[i]; cnts[i] = run; run += c; }
    }
    __syncthreads();

    int rank = cnts[t];
    #pragma unroll
    for (int q = 0; q < 2; ++q) {
        u16x8 v;
        #pragma unroll
        for (int j = 0; j < 8; ++j) {
            int f = base + q*8 + j;
            unsigned short raw = zrow[f];
            unsigned key = raw & 0x7FFFu;
            bool sel;
            if (key > tkey)       sel = true;
            else if (key == tkey) { sel = (rank < E); rank++; }
            else                  sel = false;
            v[j] = sel ? raw : (unsigned short)0;
        }
        *(u16x8*)(zp + base + q*8) = v;
    }
}

// ---------------------------------------------------------------------------
// Down-projection, fp16 16x16x32 MFMA, BK=64, 512 threads (r24-verified).
// LDS per buf: Z[2][128][32] + W[2][128][32] = 32KB; x2 = 64KB.
// ---------------------------------------------------------------------------
#define OZH 0
#define OWH (2*128*32)
#define DNBUF (4*128*32)   // 16384 elements = 32KB

__global__ __launch_bounds__(512, 4) void k_gemm_down_mfma(
    const _Float16* __restrict__ z, const _Float16* __restrict__ wdh,
    float* __restrict__ out, int tok0, int nM)
{
    __shared__ _Float16 L[2 * DNBUF];
    const int t = threadIdx.x, lane = t & 63, wid = t >> 6;   // wid 0..7

    int bid = blockIdx.x, mi, ni;
    if ((nM & 3) == 0) {
        int st = bid >> 4, lo = bid & 15, nstM = nM >> 2;
        mi = ((st % nstM) << 2) + (lo & 3);
        ni = ((st / nstM) << 2) + (lo >> 2);
    } else { mi = bid % nM; ni = bid / nM; }
    const int m0 = mi * 128, d0 = ni * 128;

    // staging: thread t fills row t>>2, chunk t&3 (linear in t)
    const int rr = t >> 2, slot = t & 3;
    const int ss = slot ^ sigma(rr);
    const size_t zoff = (size_t)(m0 + rr) * (DF*2) + ss*16;
    const size_t wof  = (size_t)(d0 + rr) * (DF*2) + ss*16;
    const char* zB = (const char*)z;
    const char* wB = (const char*)wdh;

    const int wr = wid >> 2, wc = wid & 3;   // 2 x 4 wave grid
    const int lrow = lane & 15, lk = (lane >> 4) * 8;

    int aoff[4], boff[2];
    #pragma unroll
    for (int mf = 0; mf < 4; ++mf)
        aoff[mf] = swz(wr*64 + mf*16 + lrow, lk);
    #pragma unroll
    for (int nf = 0; nf < 2; ++nf)
        boff[nf] = swz(wc*32 + nf*16 + lrow, lk);

    f32x4 acc[4][2] = {};

    #define DN_STAGE(b, kt) do {                                              \
        _Float16* Lb = L + (b) * DNBUF;                                       \
        const size_t ka = (size_t)(kt) * 128;                                 \
        _Pragma("unroll")                                                     \
        for (int s = 0; s < 2; ++s) {                                         \
            GLD16(zB + zoff + ka + s*64,                                      \
                  Lb + OZH + s*(128*32) + (wid*16)*32);                       \
            GLD16(wB + wof + ka + s*64,                                      \
                  Lb + OWH + s*(128*32) + (wid*16)*32);                       \
        }                                                                     \
    } while (0)

    DN_STAGE(0, 0);
    __syncthreads();

    int buf = 0;
    for (int kt = 0; kt < DF/64; ++kt) {
        if (kt + 1 < DF/64) DN_STAGE(buf ^ 1, kt + 1);
        const _Float16* Lb = &L[buf * DNBUF];
        #pragma unroll
        for (int s = 0; s < 2; ++s) {
            f16x8 bh[2];
            #pragma unroll
            for (int nf = 0; nf < 2; ++nf)
                bh[nf] = *(const f16x8*)&Lb[OWH + s*(128*32) + boff[nf]];
            #pragma unroll
            for (int mf = 0; mf < 4; ++mf) {
                f16x8 ah = *(const f16x8*)&Lb[OZH + s*(128*32) + aoff[mf]];
                #pragma unroll
                for (int nf = 0; nf < 2; ++nf)
                    acc[mf][nf] = MFMA16(ah, bh[nf], acc[mf][nf]);
            }
        }
        __syncthreads();
        buf ^= 1;
    }

    #pragma unroll
    for (int mf = 0; mf < 4; ++mf)
        #pragma unroll
        for (int nf = 0; nf < 2; ++nf)
            #pragma unroll
            for (int r = 0; r < 4; ++r) {
                int row = tok0 + m0 + wr*64 + mf*16 + (lane>>4)*4 + r;
                int col = d0 + wc*32 + nf*16 + lrow;
                out[(size_t)row*NE + col] = acc[mf][nf][r];
            }
    #undef DN_STAGE
}

// ---------------------------------------------------------------------------
extern "C" void kernel_launch(void* const* d_in, const int* in_sizes, int n_in,
                              void* d_out, int out_size, void* d_ws, size_t ws_size,
                              hipStream_t stream)
{
    const float* x  = (const float*)d_in[0];
    const float* Wg = (const float*)d_in[1];
    const float* Wu = (const float*)d_in[2];
    const float* Wd = (const float*)d_in[3];
    float* out = (float*)d_out;

    // fixed-size weights: gh/uh (DF*NE f16) + wdh (NE*DF f16) = 3 arrays
    const size_t wElems = (size_t)DF * NE;
    const size_t fixedBytes = wElems * 2 * 3;   // 25 MB

    // chunk tokens: need z fp16 (CT*DF*2) + xh (CT*NE*2) + fixed
    int CT = NTOK;
    while (CT > 128 &&
           (size_t)CT*DF*2 + (size_t)CT*NE*2 + fixedBytes > ws_size) CT >>= 1;

    char* wsb = (char*)d_ws;
    _Float16* zbuf = (_Float16*)wsb;
    _Float16* xh   = (_Float16*)(wsb + (size_t)CT*DF*2);
    _Float16* gh   = xh + (size_t)CT*NE;
    _Float16* uh   = gh + wElems;
    _Float16* wdh  = uh + wElems;

    const int nw8 = (int)(wElems / 8);

    for (int tok0 = 0; tok0 < NTOK; tok0 += CT) {
        int nM  = CT / 128;
        int nx8 = CT * NE / 8;
        int nPrep = 3*nw8 + nx8;
        k_prep<<<dim3((nPrep+255)/256), 256, 0, stream>>>(
            Wg, Wu, Wd, x + (size_t)tok0*NE, gh, uh, wdh, xh, nw8, nx8);
        k_gemm_gu_mfma  <<<dim3(nM * (DF/128)), 512, 0, stream>>>(xh, gh, uh, zbuf, nM);
        k_topk_mask16   <<<dim3(CT),            256, 0, stream>>>(zbuf);
        k_gemm_down_mfma<<<dim3(nM * (NE/128)), 512, 0, stream>>>(zbuf, wdh, out, tok0, nM);
    }
}

// Round 27
// 674.885 us; speedup vs baseline: 2.3017x; 2.3017x over previous
//
#include <hip/hip_runtime.h>
#include <cstdint>
#include <cstddef>

#define NE   1024    // N_EMBD
#define DF   4096    // D_FF
#define KACT 1024    // K_ACTIVE
#define NTOK 16384   // B*S

typedef _Float16       f16x8  __attribute__((ext_vector_type(8)));
typedef unsigned short u16x8  __attribute__((ext_vector_type(8)));
typedef float          f32x4  __attribute__((ext_vector_type(4)));

#define MFMA16(a,b,c) __builtin_amdgcn_mfma_f32_16x16x32_f16(a,b,c,0,0,0)

// async global->LDS, 16B per lane; LDS dest = uniform base + lane*16 (linear)
#define GLD16(gp, lp) __builtin_amdgcn_global_load_lds( \
    (const __attribute__((address_space(1))) unsigned int*)(gp), \
    (__attribute__((address_space(3))) unsigned int*)(lp), 16, 0, 0)

// LDS tiles are [rows][32] f16 (64 B rows, 4x 16B chunks).
// 16x16 frags + sigma=(r>>1)&3: measured 0 bank conflicts (r10-r24).
// global_load_lds fills linearly; the same involution pre-swizzles the
// per-lane GLOBAL source chunk (rule 21).
__device__ __forceinline__ int sigma(int row) {
    return (row >> 1) & 3;
}
__device__ __forceinline__ int swz(int row, int lk) {
    return row * 32 + ((((lk) >> 3) ^ sigma(row)) << 3);
}

// ---------------------------------------------------------------------------
// Fused prep (1 launch): Wg->gh, Wu->uh, Wd->wdh, x->xh (all fp32->fp16).
// Single-fp16 gu validated r25: absmax 0.0586 < 0.06875.
// ---------------------------------------------------------------------------
__global__ __launch_bounds__(256) void k_prep(
    const float* __restrict__ Wg, const float* __restrict__ Wu,
    const float* __restrict__ Wd, const float* __restrict__ x,
    _Float16* __restrict__ gh, _Float16* __restrict__ uh,
    _Float16* __restrict__ wdh, _Float16* __restrict__ xh,
    int nw8, int nx8)
{
    int i = blockIdx.x * 256 + threadIdx.x;
    const float* s; _Float16* dh; int j;
    if (i < nw8)            { s = Wg; dh = gh;  j = i; }
    else if (i < 2*nw8)     { s = Wu; dh = uh;  j = i - nw8; }
    else if (i < 3*nw8)     { s = Wd; dh = wdh; j = i - 2*nw8; }
    else if (i < 3*nw8+nx8) { s = x;  dh = xh;  j = i - 3*nw8; }
    else return;
    float4 a = ((const float4*)s)[2*j], b = ((const float4*)s)[2*j+1];
    float f[8] = {a.x,a.y,a.z,a.w,b.x,b.y,b.z,b.w};
    f16x8 hh;
    #pragma unroll
    for (int q = 0; q < 8; ++q) hh[q] = (_Float16)f[q];
    ((f16x8*)dh)[j] = hh;
}

// ---------------------------------------------------------------------------
// Up-projection, SINGLE-fp16 MFMA. 16x16x32 frags, 128x128 tile, 512 thr,
// 8 waves (2x4), per-wave 64 tok x 32 ff for g and u: 16 MFMA16 + 8 ds_read
// + 3 GLD16/lane per K-step. LDS per buf: XH/GH/UH [128][32] = 24KB; x2=48KB.
// launch_bounds (512,4): 128-VGPR budget, no spill (r23/r24-proven;
// (512,6) caused accumulator spill — r25 post-mortem).
// ---------------------------------------------------------------------------
#define OXH 0
#define OGH (128*32)
#define OUH (2*128*32)
#define GUBUF (3*128*32)   // 12288 elements = 24KB

__global__ __launch_bounds__(512, 4) void k_gemm_gu_mfma(
    const _Float16* __restrict__ xh,
    const _Float16* __restrict__ gh, const _Float16* __restrict__ uh,
    _Float16* __restrict__ z, int nM)
{
    __shared__ _Float16 L[2 * GUBUF];
    const int t = threadIdx.x, lane = t & 63, wid = t >> 6;   // wid 0..7

    // 4x4 supertile swizzle for L2 locality
    int bid = blockIdx.x, mi, ni;
    if ((nM & 3) == 0) {
        int st = bid >> 4, lo = bid & 15, nstM = nM >> 2;
        mi = ((st % nstM) << 2) + (lo & 3);
        ni = ((st / nstM) << 2) + (lo >> 2);
    } else { mi = bid % nM; ni = bid / nM; }
    const int m0 = mi * 128, f0 = ni * 128;

    // staging: thread t fills row t>>2, chunk t&3 (linear in t); wave w
    // covers rows [w*16, w*16+16). Source chunk pre-swizzled.
    const int rr = t >> 2, slot = t & 3;
    const int ss = slot ^ sigma(rr);
    const size_t xoff = (size_t)(m0 + rr) * (NE*2) + ss*16;
    const size_t goff = (size_t)(f0 + rr) * (NE*2) + ss*16;
    const char* xhB = (const char*)xh;
    const char* ghB = (const char*)gh;
    const char* uhB = (const char*)uh;

    const int wr = wid >> 2, wc = wid & 3;   // 2 x 4 wave grid
    const int lrow = lane & 15, lk = (lane >> 4) * 8;   // 16x16 frag coords

    int aoff[4], boff[2];
    #pragma unroll
    for (int mf = 0; mf < 4; ++mf)
        aoff[mf] = swz(wr*64 + mf*16 + lrow, lk);
    #pragma unroll
    for (int nf = 0; nf < 2; ++nf)
        boff[nf] = swz(wc*32 + nf*16 + lrow, lk);

    f32x4 accg[4][2] = {}, accu[4][2] = {};

    #define GU_STAGE(b, kt) do {                                              \
        _Float16* Lb = L + (b) * GUBUF;                                       \
        const size_t ka = (size_t)(kt) * 64;                                  \
        GLD16(xhB + xoff + ka, Lb + OXH + (wid*16)*32);                       \
        GLD16(ghB + goff + ka, Lb + OGH + (wid*16)*32);                       \
        GLD16(uhB + goff + ka, Lb + OUH + (wid*16)*32);                       \
    } while (0)

    GU_STAGE(0, 0);
    __syncthreads();

    int buf = 0;
    for (int kt = 0; kt < 32; ++kt) {
        if (kt + 1 < 32) GU_STAGE(buf ^ 1, kt + 1);
        const _Float16* Lb = &L[buf * GUBUF];
        f16x8 bg[2], bu[2];
        #pragma unroll
        for (int nf = 0; nf < 2; ++nf) {
            bg[nf] = *(const f16x8*)&Lb[OGH + boff[nf]];
            bu[nf] = *(const f16x8*)&Lb[OUH + boff[nf]];
        }
        #pragma unroll
        for (int mf = 0; mf < 4; ++mf) {
            f16x8 ah = *(const f16x8*)&Lb[OXH + aoff[mf]];
            #pragma unroll
            for (int nf = 0; nf < 2; ++nf) {
                accg[mf][nf] = MFMA16(ah, bg[nf], accg[mf][nf]);
                accu[mf][nf] = MFMA16(ah, bu[nf], accu[mf][nf]);
            }
        }
        __syncthreads();
        buf ^= 1;
    }

    // epilogue: silu(g)*u with native exp; 16x16 C-layout store
    #pragma unroll
    for (int mf = 0; mf < 4; ++mf)
        #pragma unroll
        for (int nf = 0; nf < 2; ++nf)
            #pragma unroll
            for (int r = 0; r < 4; ++r) {
                int row = m0 + wr*64 + mf*16 + (lane>>4)*4 + r;
                int col = f0 + wc*32 + nf*16 + lrow;
                float g = accg[mf][nf][r], u = accu[mf][nf][r];
                float sg = g / (1.0f + __expf(-g));
                z[(size_t)row*DF + col] = (_Float16)(sg * u);
            }
    #undef GU_STAGE
}

// ---------------------------------------------------------------------------
// Exact per-token top-K mask on fp16 z: 2-pass radix select on the 15-bit
// magnitude key; stable ties by ascending index.
// r27 (replay-divergence fix): SINGLE-WRITER pipeline — reads z_in (written
// only by gu), writes masked row to z_out (read only by down). No buffer is
// mutated after being produced within a call.
// ---------------------------------------------------------------------------
__global__ __launch_bounds__(256) void k_topk_mask16(
    const _Float16* __restrict__ z_in, _Float16* __restrict__ z_out)
{
    __shared__ unsigned short zrow[DF];
    __shared__ unsigned hist[256];
    __shared__ int      cnts[256];
    __shared__ unsigned s_b1;
    __shared__ unsigned s_tkey;
    __shared__ int      s_remaining;

    const int t = threadIdx.x;
    const unsigned short* zpi = (const unsigned short*)(z_in  + (size_t)blockIdx.x * DF);
    unsigned short*       zpo = (unsigned short*)      (z_out + (size_t)blockIdx.x * DF);

    for (int i = t; i < DF/8; i += 256) {
        ((ushort4*)zrow)[2*i]   = ((const ushort4*)zpi)[2*i];
        ((ushort4*)zrow)[2*i+1] = ((const ushort4*)zpi)[2*i+1];
    }
    if (t == 0) s_remaining = KACT;
    __syncthreads();

    hist[t] = 0u;
    __syncthreads();
    {
        const int base = t * 16;
        #pragma unroll
        for (int j = 0; j < 16; ++j) {
            unsigned key = zrow[base + j] & 0x7FFFu;
            atomicAdd(&hist[key >> 7], 1u);
        }
    }
    __syncthreads();
    if (t == 0) {
        int rem = s_remaining;
        int b = 255;
        for (; b > 0; --b) {
            int c = (int)hist[b];
            if (rem - c <= 0) break;
            rem -= c;
        }
        s_b1 = (unsigned)b;
        s_remaining = rem;
    }
    __syncthreads();

    const unsigned b1 = s_b1;
    hist[t] = 0u;
    __syncthreads();
    {
        const int base = t * 16;
        #pragma unroll
        for (int j = 0; j < 16; ++j) {
            unsigned key = zrow[base + j] & 0x7FFFu;
            if ((key >> 7) == b1) atomicAdd(&hist[key & 0x7Fu], 1u);
        }
    }
    __syncthreads();
    if (t == 0) {
        int rem = s_remaining;
        int b = 127;
        for (; b > 0; --b) {
            int c = (int)hist[b];
            if (rem - c <= 0) break;
            rem -= c;
        }
        s_tkey = (b1 << 7) | (unsigned)b;
        s_remaining = rem;
    }
    __syncthreads();

    const unsigned tkey = s_tkey;
    const int      E    = s_remaining;

    const int base = t * 16;
    int cnt = 0;
    #pragma unroll
    for (int j = 0; j < 16; ++j)
        if ((zrow[base + j] & 0x7FFFu) == tkey) cnt++;
    cnts[t] = cnt;
    __syncthreads();
    if (t == 0) {
        int run = 0;
        for (int i = 0; i < 256; ++i) { int c = cnts[i]; cnts[i] = run; run += c; }
    }
    __syncthreads();

    int rank = cnts[t];
    #pragma unroll
    for (int q = 0; q < 2; ++q) {
        u16x8 v;
        #pragma unroll
        for (int j = 0; j < 8; ++j) {
            int f = base + q*8 + j;
            unsigned short raw = zrow[f];
            unsigned key = raw & 0x7FFFu;
            bool sel;
            if (key > tkey)       sel = true;
            else if (key == tkey) { sel = (rank < E); rank++; }
            else                  sel = false;
            v[j] = sel ? raw : (unsigned short)0;
        }
        *(u16x8*)(zpo + base + q*8) = v;
    }
}

// ---------------------------------------------------------------------------
// Down-projection, fp16 16x16x32 MFMA, BK=64, 512 threads (r24-verified).
// Reads the masked zm (single-writer). LDS per buf: 32KB; x2 = 64KB.
// ---------------------------------------------------------------------------
#define OZH 0
#define OWH (2*128*32)
#define DNBUF (4*128*32)   // 16384 elements = 32KB

__global__ __launch_bounds__(512, 4) void k_gemm_down_mfma(
    const _Float16* __restrict__ z, const _Float16* __restrict__ wdh,
    float* __restrict__ out, int tok0, int nM)
{
    __shared__ _Float16 L[2 * DNBUF];
    const int t = threadIdx.x, lane = t & 63, wid = t >> 6;   // wid 0..7

    int bid = blockIdx.x, mi, ni;
    if ((nM & 3) == 0) {
        int st = bid >> 4, lo = bid & 15, nstM = nM >> 2;
        mi = ((st % nstM) << 2) + (lo & 3);
        ni = ((st / nstM) << 2) + (lo >> 2);
    } else { mi = bid % nM; ni = bid / nM; }
    const int m0 = mi * 128, d0 = ni * 128;

    // staging: thread t fills row t>>2, chunk t&3 (linear in t)
    const int rr = t >> 2, slot = t & 3;
    const int ss = slot ^ sigma(rr);
    const size_t zoff = (size_t)(m0 + rr) * (DF*2) + ss*16;
    const size_t wof  = (size_t)(d0 + rr) * (DF*2) + ss*16;
    const char* zB = (const char*)z;
    const char* wB = (const char*)wdh;

    const int wr = wid >> 2, wc = wid & 3;   // 2 x 4 wave grid
    const int lrow = lane & 15, lk = (lane >> 4) * 8;

    int aoff[4], boff[2];
    #pragma unroll
    for (int mf = 0; mf < 4; ++mf)
        aoff[mf] = swz(wr*64 + mf*16 + lrow, lk);
    #pragma unroll
    for (int nf = 0; nf < 2; ++nf)
        boff[nf] = swz(wc*32 + nf*16 + lrow, lk);

    f32x4 acc[4][2] = {};

    #define DN_STAGE(b, kt) do {                                              \
        _Float16* Lb = L + (b) * DNBUF;                                       \
        const size_t ka = (size_t)(kt) * 128;                                 \
        _Pragma("unroll")                                                     \
        for (int s = 0; s < 2; ++s) {                                         \
            GLD16(zB + zoff + ka + s*64,                                      \
                  Lb + OZH + s*(128*32) + (wid*16)*32);                       \
            GLD16(wB + wof + ka + s*64,                                      \
                  Lb + OWH + s*(128*32) + (wid*16)*32);                       \
        }                                                                     \
    } while (0)

    DN_STAGE(0, 0);
    __syncthreads();

    int buf = 0;
    for (int kt = 0; kt < DF/64; ++kt) {
        if (kt + 1 < DF/64) DN_STAGE(buf ^ 1, kt + 1);
        const _Float16* Lb = &L[buf * DNBUF];
        #pragma unroll
        for (int s = 0; s < 2; ++s) {
            f16x8 bh[2];
            #pragma unroll
            for (int nf = 0; nf < 2; ++nf)
                bh[nf] = *(const f16x8*)&Lb[OWH + s*(128*32) + boff[nf]];
            #pragma unroll
            for (int mf = 0; mf < 4; ++mf) {
                f16x8 ah = *(const f16x8*)&Lb[OZH + s*(128*32) + aoff[mf]];
                #pragma unroll
                for (int nf = 0; nf < 2; ++nf)
                    acc[mf][nf] = MFMA16(ah, bh[nf], acc[mf][nf]);
            }
        }
        __syncthreads();
        buf ^= 1;
    }

    #pragma unroll
    for (int mf = 0; mf < 4; ++mf)
        #pragma unroll
        for (int nf = 0; nf < 2; ++nf)
            #pragma unroll
            for (int r = 0; r < 4; ++r) {
                int row = tok0 + m0 + wr*64 + mf*16 + (lane>>4)*4 + r;
                int col = d0 + wc*32 + nf*16 + lrow;
                out[(size_t)row*NE + col] = acc[mf][nf][r];
            }
    #undef DN_STAGE
}

// ---------------------------------------------------------------------------
extern "C" void kernel_launch(void* const* d_in, const int* in_sizes, int n_in,
                              void* d_out, int out_size, void* d_ws, size_t ws_size,
                              hipStream_t stream)
{
    const float* x  = (const float*)d_in[0];
    const float* Wg = (const float*)d_in[1];
    const float* Wu = (const float*)d_in[2];
    const float* Wd = (const float*)d_in[3];
    float* out = (float*)d_out;

    // fixed-size weights: gh/uh (DF*NE f16) + wdh (NE*DF f16) = 3 arrays
    const size_t wElems = (size_t)DF * NE;
    const size_t fixedBytes = wElems * 2 * 3;   // 25 MB

    // chunk tokens: need z (CT*DF*2) + zm (CT*DF*2) + xh (CT*NE*2) + fixed
    int CT = NTOK;
    while (CT > 128 &&
           (size_t)CT*DF*4 + (size_t)CT*NE*2 + fixedBytes > ws_size) CT >>= 1;

    char* wsb = (char*)d_ws;
    _Float16* zbuf = (_Float16*)wsb;                          // gu output
    _Float16* zm   = zbuf + (size_t)CT*DF;                    // topk output
    _Float16* xh   = zm   + (size_t)CT*DF;
    _Float16* gh   = xh + (size_t)CT*NE;
    _Float16* uh   = gh + wElems;
    _Float16* wdh  = uh + wElems;

    const int nw8 = (int)(wElems / 8);

    for (int tok0 = 0; tok0 < NTOK; tok0 += CT) {
        int nM  = CT / 128;
        int nx8 = CT * NE / 8;
        int nPrep = 3*nw8 + nx8;
        k_prep<<<dim3((nPrep+255)/256), 256, 0, stream>>>(
            Wg, Wu, Wd, x + (size_t)tok0*NE, gh, uh, wdh, xh, nw8, nx8);
        k_gemm_gu_mfma  <<<dim3(nM * (DF/128)), 512, 0, stream>>>(xh, gh, uh, zbuf, nM);
        k_topk_mask16   <<<dim3(CT),            256, 0, stream>>>(zbuf, zm);
        k_gemm_down_mfma<<<dim3(nM * (NE/128)), 512, 0, stream>>>(zm, wdh, out, tok0, nM);
    }
}

// Round 28
// 664.741 us; speedup vs baseline: 2.3368x; 1.0153x over previous
//
#include <hip/hip_runtime.h>
#include <cstdint>
#include <cstddef>

#define NE   1024    // N_EMBD
#define DF   4096    // D_FF
#define KACT 1024    // K_ACTIVE
#define NTOK 16384   // B*S

typedef _Float16       f16x8  __attribute__((ext_vector_type(8)));
typedef unsigned short u16x8  __attribute__((ext_vector_type(8)));
typedef float          f32x4  __attribute__((ext_vector_type(4)));

#define MFMA16(a,b,c) __builtin_amdgcn_mfma_f32_16x16x32_f16(a,b,c,0,0,0)

// async global->LDS, 16B per lane; LDS dest = uniform base + lane*16 (linear)
#define GLD16(gp, lp) __builtin_amdgcn_global_load_lds( \
    (const __attribute__((address_space(1))) unsigned int*)(gp), \
    (__attribute__((address_space(3))) unsigned int*)(lp), 16, 0, 0)

// LDS tiles are [rows][32] f16 (64 B rows, 4x 16B chunks).
// 16x16 frags + sigma=(r>>1)&3: measured 0 bank conflicts (r10-r27).
// global_load_lds fills linearly; the same involution pre-swizzles the
// per-lane GLOBAL source chunk (rule 21).
__device__ __forceinline__ int sigma(int row) {
    return (row >> 1) & 3;
}
__device__ __forceinline__ int swz(int row, int lk) {
    return row * 32 + ((((lk) >> 3) ^ sigma(row)) << 3);
}

// ---------------------------------------------------------------------------
// One-time weight prep (hoisted out of the chunk loop — r28): Wg->gh,
// Wu->uh, Wd->wdh (fp32->fp16).
// ---------------------------------------------------------------------------
__global__ __launch_bounds__(256) void k_prep_w(
    const float* __restrict__ Wg, const float* __restrict__ Wu,
    const float* __restrict__ Wd,
    _Float16* __restrict__ gh, _Float16* __restrict__ uh,
    _Float16* __restrict__ wdh, int nw8)
{
    int i = blockIdx.x * 256 + threadIdx.x;
    const float* s; _Float16* dh; int j;
    if (i < nw8)        { s = Wg; dh = gh;  j = i; }
    else if (i < 2*nw8) { s = Wu; dh = uh;  j = i - nw8; }
    else if (i < 3*nw8) { s = Wd; dh = wdh; j = i - 2*nw8; }
    else return;
    float4 a = ((const float4*)s)[2*j], b = ((const float4*)s)[2*j+1];
    float f[8] = {a.x,a.y,a.z,a.w,b.x,b.y,b.z,b.w};
    f16x8 hh;
    #pragma unroll
    for (int q = 0; q < 8; ++q) hh[q] = (_Float16)f[q];
    ((f16x8*)dh)[j] = hh;
}

// per-chunk x prep: x -> xh (fp32->fp16)
__global__ __launch_bounds__(256) void k_prep_x(
    const float* __restrict__ x, _Float16* __restrict__ xh, int nx8)
{
    int i = blockIdx.x * 256 + threadIdx.x;
    if (i >= nx8) return;
    float4 a = ((const float4*)x)[2*i], b = ((const float4*)x)[2*i+1];
    float f[8] = {a.x,a.y,a.z,a.w,b.x,b.y,b.z,b.w};
    f16x8 hh;
    #pragma unroll
    for (int q = 0; q < 8; ++q) hh[q] = (_Float16)f[q];
    ((f16x8*)xh)[i] = hh;
}

// ---------------------------------------------------------------------------
// Up-projection, SINGLE-fp16 MFMA (validated r25/r27: absmax 0.0586).
// 16x16x32 frags, 128x128 tile, 512 thr, 8 waves (2x4), per-wave 64x32 for
// g and u: 16 MFMA16 + 8 ds_read + 3 GLD16/lane per K-step.
// LDS per buf: XH/GH/UH [128][32] = 24KB; x2 = 48KB.
// launch_bounds (512,4): no spill (r25 post-mortem: (512,6) spilled acc).
// ---------------------------------------------------------------------------
#define OXH 0
#define OGH (128*32)
#define OUH (2*128*32)
#define GUBUF (3*128*32)   // 12288 elements = 24KB

__global__ __launch_bounds__(512, 4) void k_gemm_gu_mfma(
    const _Float16* __restrict__ xh,
    const _Float16* __restrict__ gh, const _Float16* __restrict__ uh,
    _Float16* __restrict__ z, int nM)
{
    __shared__ _Float16 L[2 * GUBUF];
    const int t = threadIdx.x, lane = t & 63, wid = t >> 6;   // wid 0..7

    // 4x4 supertile swizzle for L2 locality
    int bid = blockIdx.x, mi, ni;
    if ((nM & 3) == 0) {
        int st = bid >> 4, lo = bid & 15, nstM = nM >> 2;
        mi = ((st % nstM) << 2) + (lo & 3);
        ni = ((st / nstM) << 2) + (lo >> 2);
    } else { mi = bid % nM; ni = bid / nM; }
    const int m0 = mi * 128, f0 = ni * 128;

    // staging: thread t fills row t>>2, chunk t&3 (linear in t); wave w
    // covers rows [w*16, w*16+16). Source chunk pre-swizzled.
    const int rr = t >> 2, slot = t & 3;
    const int ss = slot ^ sigma(rr);
    const size_t xoff = (size_t)(m0 + rr) * (NE*2) + ss*16;
    const size_t goff = (size_t)(f0 + rr) * (NE*2) + ss*16;
    const char* xhB = (const char*)xh;
    const char* ghB = (const char*)gh;
    const char* uhB = (const char*)uh;

    const int wr = wid >> 2, wc = wid & 3;   // 2 x 4 wave grid
    const int lrow = lane & 15, lk = (lane >> 4) * 8;   // 16x16 frag coords

    int aoff[4], boff[2];
    #pragma unroll
    for (int mf = 0; mf < 4; ++mf)
        aoff[mf] = swz(wr*64 + mf*16 + lrow, lk);
    #pragma unroll
    for (int nf = 0; nf < 2; ++nf)
        boff[nf] = swz(wc*32 + nf*16 + lrow, lk);

    f32x4 accg[4][2] = {}, accu[4][2] = {};

    #define GU_STAGE(b, kt) do {                                              \
        _Float16* Lb = L + (b) * GUBUF;                                       \
        const size_t ka = (size_t)(kt) * 64;                                  \
        GLD16(xhB + xoff + ka, Lb + OXH + (wid*16)*32);                       \
        GLD16(ghB + goff + ka, Lb + OGH + (wid*16)*32);                       \
        GLD16(uhB + goff + ka, Lb + OUH + (wid*16)*32);                       \
    } while (0)

    GU_STAGE(0, 0);
    __syncthreads();

    int buf = 0;
    for (int kt = 0; kt < 32; ++kt) {
        if (kt + 1 < 32) GU_STAGE(buf ^ 1, kt + 1);
        const _Float16* Lb = &L[buf * GUBUF];
        f16x8 bg[2], bu[2];
        #pragma unroll
        for (int nf = 0; nf < 2; ++nf) {
            bg[nf] = *(const f16x8*)&Lb[OGH + boff[nf]];
            bu[nf] = *(const f16x8*)&Lb[OUH + boff[nf]];
        }
        #pragma unroll
        for (int mf = 0; mf < 4; ++mf) {
            f16x8 ah = *(const f16x8*)&Lb[OXH + aoff[mf]];
            #pragma unroll
            for (int nf = 0; nf < 2; ++nf) {
                accg[mf][nf] = MFMA16(ah, bg[nf], accg[mf][nf]);
                accu[mf][nf] = MFMA16(ah, bu[nf], accu[mf][nf]);
            }
        }
        __syncthreads();
        buf ^= 1;
    }

    // epilogue: silu(g)*u with native exp; 16x16 C-layout store
    #pragma unroll
    for (int mf = 0; mf < 4; ++mf)
        #pragma unroll
        for (int nf = 0; nf < 2; ++nf)
            #pragma unroll
            for (int r = 0; r < 4; ++r) {
                int row = m0 + wr*64 + mf*16 + (lane>>4)*4 + r;
                int col = f0 + wc*32 + nf*16 + lrow;
                float g = accg[mf][nf][r], u = accu[mf][nf][r];
                float sg = g / (1.0f + __expf(-g));
                z[(size_t)row*DF + col] = (_Float16)(sg * u);
            }
    #undef GU_STAGE
}

// ---------------------------------------------------------------------------
// Exact per-token top-K mask on fp16 z: 2-pass radix select on the 15-bit
// magnitude key; stable ties by ascending index. Single-writer pipeline
// (r27-verified): reads z_in (gu's output), writes masked row to z_out.
// ---------------------------------------------------------------------------
__global__ __launch_bounds__(256) void k_topk_mask16(
    const _Float16* __restrict__ z_in, _Float16* __restrict__ z_out)
{
    __shared__ unsigned short zrow[DF];
    __shared__ unsigned hist[256];
    __shared__ int      cnts[256];
    __shared__ unsigned s_b1;
    __shared__ unsigned s_tkey;
    __shared__ int      s_remaining;

    const int t = threadIdx.x;
    const unsigned short* zpi = (const unsigned short*)(z_in  + (size_t)blockIdx.x * DF);
    unsigned short*       zpo = (unsigned short*)      (z_out + (size_t)blockIdx.x * DF);

    for (int i = t; i < DF/8; i += 256) {
        ((ushort4*)zrow)[2*i]   = ((const ushort4*)zpi)[2*i];
        ((ushort4*)zrow)[2*i+1] = ((const ushort4*)zpi)[2*i+1];
    }
    if (t == 0) s_remaining = KACT;
    __syncthreads();

    hist[t] = 0u;
    __syncthreads();
    {
        const int base = t * 16;
        #pragma unroll
        for (int j = 0; j < 16; ++j) {
            unsigned key = zrow[base + j] & 0x7FFFu;
            atomicAdd(&hist[key >> 7], 1u);
        }
    }
    __syncthreads();
    if (t == 0) {
        int rem = s_remaining;
        int b = 255;
        for (; b > 0; --b) {
            int c = (int)hist[b];
            if (rem - c <= 0) break;
            rem -= c;
        }
        s_b1 = (unsigned)b;
        s_remaining = rem;
    }
    __syncthreads();

    const unsigned b1 = s_b1;
    hist[t] = 0u;
    __syncthreads();
    {
        const int base = t * 16;
        #pragma unroll
        for (int j = 0; j < 16; ++j) {
            unsigned key = zrow[base + j] & 0x7FFFu;
            if ((key >> 7) == b1) atomicAdd(&hist[key & 0x7Fu], 1u);
        }
    }
    __syncthreads();
    if (t == 0) {
        int rem = s_remaining;
        int b = 127;
        for (; b > 0; --b) {
            int c = (int)hist[b];
            if (rem - c <= 0) break;
            rem -= c;
        }
        s_tkey = (b1 << 7) | (unsigned)b;
        s_remaining = rem;
    }
    __syncthreads();

    const unsigned tkey = s_tkey;
    const int      E    = s_remaining;

    const int base = t * 16;
    int cnt = 0;
    #pragma unroll
    for (int j = 0; j < 16; ++j)
        if ((zrow[base + j] & 0x7FFFu) == tkey) cnt++;
    cnts[t] = cnt;
    __syncthreads();
    if (t == 0) {
        int run = 0;
        for (int i = 0; i < 256; ++i) { int c = cnts[i]; cnts[i] = run; run += c; }
    }
    __syncthreads();

    int rank = cnts[t];
    #pragma unroll
    for (int q = 0; q < 2; ++q) {
        u16x8 v;
        #pragma unroll
        for (int j = 0; j < 8; ++j) {
            int f = base + q*8 + j;
            unsigned short raw = zrow[f];
            unsigned key = raw & 0x7FFFu;
            bool sel;
            if (key > tkey)       sel = true;
            else if (key == tkey) { sel = (rank < E); rank++; }
            else                  sel = false;
            v[j] = sel ? raw : (unsigned short)0;
        }
        *(u16x8*)(zpo + base + q*8) = v;
    }
}

// ---------------------------------------------------------------------------
// Down-projection, fp16 16x16x32 MFMA, BK=64, 512 threads (r24/r27-verified).
// Reads the masked zm (single-writer). LDS per buf: 32KB; x2 = 64KB.
// ---------------------------------------------------------------------------
#define OZH 0
#define OWH (2*128*32)
#define DNBUF (4*128*32)   // 16384 elements = 32KB

__global__ __launch_bounds__(512, 4) void k_gemm_down_mfma(
    const _Float16* __restrict__ z, const _Float16* __restrict__ wdh,
    float* __restrict__ out, int tok0, int nM)
{
    __shared__ _Float16 L[2 * DNBUF];
    const int t = threadIdx.x, lane = t & 63, wid = t >> 6;   // wid 0..7

    int bid = blockIdx.x, mi, ni;
    if ((nM & 3) == 0) {
        int st = bid >> 4, lo = bid & 15, nstM = nM >> 2;
        mi = ((st % nstM) << 2) + (lo & 3);
        ni = ((st / nstM) << 2) + (lo >> 2);
    } else { mi = bid % nM; ni = bid / nM; }
    const int m0 = mi * 128, d0 = ni * 128;

    // staging: thread t fills row t>>2, chunk t&3 (linear in t)
    const int rr = t >> 2, slot = t & 3;
    const int ss = slot ^ sigma(rr);
    const size_t zoff = (size_t)(m0 + rr) * (DF*2) + ss*16;
    const size_t wof  = (size_t)(d0 + rr) * (DF*2) + ss*16;
    const char* zB = (const char*)z;
    const char* wB = (const char*)wdh;

    const int wr = wid >> 2, wc = wid & 3;   // 2 x 4 wave grid
    const int lrow = lane & 15, lk = (lane >> 4) * 8;

    int aoff[4], boff[2];
    #pragma unroll
    for (int mf = 0; mf < 4; ++mf)
        aoff[mf] = swz(wr*64 + mf*16 + lrow, lk);
    #pragma unroll
    for (int nf = 0; nf < 2; ++nf)
        boff[nf] = swz(wc*32 + nf*16 + lrow, lk);

    f32x4 acc[4][2] = {};

    #define DN_STAGE(b, kt) do {                                              \
        _Float16* Lb = L + (b) * DNBUF;                                       \
        const size_t ka = (size_t)(kt) * 128;                                 \
        _Pragma("unroll")                                                     \
        for (int s = 0; s < 2; ++s) {                                         \
            GLD16(zB + zoff + ka + s*64,                                      \
                  Lb + OZH + s*(128*32) + (wid*16)*32);                       \
            GLD16(wB + wof + ka + s*64,                                      \
                  Lb + OWH + s*(128*32) + (wid*16)*32);                       \
        }                                                                     \
    } while (0)

    DN_STAGE(0, 0);
    __syncthreads();

    int buf = 0;
    for (int kt = 0; kt < DF/64; ++kt) {
        if (kt + 1 < DF/64) DN_STAGE(buf ^ 1, kt + 1);
        const _Float16* Lb = &L[buf * DNBUF];
        #pragma unroll
        for (int s = 0; s < 2; ++s) {
            f16x8 bh[2];
            #pragma unroll
            for (int nf = 0; nf < 2; ++nf)
                bh[nf] = *(const f16x8*)&Lb[OWH + s*(128*32) + boff[nf]];
            #pragma unroll
            for (int mf = 0; mf < 4; ++mf) {
                f16x8 ah = *(const f16x8*)&Lb[OZH + s*(128*32) + aoff[mf]];
                #pragma unroll
                for (int nf = 0; nf < 2; ++nf)
                    acc[mf][nf] = MFMA16(ah, bh[nf], acc[mf][nf]);
            }
        }
        __syncthreads();
        buf ^= 1;
    }

    #pragma unroll
    for (int mf = 0; mf < 4; ++mf)
        #pragma unroll
        for (int nf = 0; nf < 2; ++nf)
            #pragma unroll
            for (int r = 0; r < 4; ++r) {
                int row = tok0 + m0 + wr*64 + mf*16 + (lane>>4)*4 + r;
                int col = d0 + wc*32 + nf*16 + lrow;
                out[(size_t)row*NE + col] = acc[mf][nf][r];
            }
    #undef DN_STAGE
}

// ---------------------------------------------------------------------------
extern "C" void kernel_launch(void* const* d_in, const int* in_sizes, int n_in,
                              void* d_out, int out_size, void* d_ws, size_t ws_size,
                              hipStream_t stream)
{
    const float* x  = (const float*)d_in[0];
    const float* Wg = (const float*)d_in[1];
    const float* Wu = (const float*)d_in[2];
    const float* Wd = (const float*)d_in[3];
    float* out = (float*)d_out;

    // fixed-size weights: gh/uh (DF*NE f16) + wdh (NE*DF f16) = 3 arrays
    const size_t wElems = (size_t)DF * NE;
    const size_t fixedBytes = wElems * 2 * 3;   // 25 MB

    // chunk tokens: need z (CT*DF*2) + zm (CT*DF*2) + xh (CT*NE*2) + fixed
    int CT = NTOK;
    while (CT > 128 &&
           (size_t)CT*DF*4 + (size_t)CT*NE*2 + fixedBytes > ws_size) CT >>= 1;

    char* wsb = (char*)d_ws;
    _Float16* zbuf = (_Float16*)wsb;                          // gu output
    _Float16* zm   = zbuf + (size_t)CT*DF;                    // topk output
    _Float16* xh   = zm   + (size_t)CT*DF;
    _Float16* gh   = xh + (size_t)CT*NE;
    _Float16* uh   = gh + wElems;
    _Float16* wdh  = uh + wElems;

    const int nw8 = (int)(wElems / 8);

    // one-time weight prep (hoisted — r28; was duplicated per chunk)
    k_prep_w<<<dim3((3*nw8 + 255)/256), 256, 0, stream>>>(
        Wg, Wu, Wd, gh, uh, wdh, nw8);

    for (int tok0 = 0; tok0 < NTOK; tok0 += CT) {
        int nM  = CT / 128;
        int nx8 = CT * NE / 8;
        k_prep_x<<<dim3((nx8 + 255)/256), 256, 0, stream>>>(
            x + (size_t)tok0*NE, xh, nx8);
        k_gemm_gu_mfma  <<<dim3(nM * (DF/128)), 512, 0, stream>>>(xh, gh, uh, zbuf, nM);
        k_topk_mask16   <<<dim3(CT),            256, 0, stream>>>(zbuf, zm);
        k_gemm_down_mfma<<<dim3(nM * (NE/128)), 512, 0, stream>>>(zm, wdh, out, tok0, nM);
    }
}